// Round 5
// baseline (283.494 us; speedup 1.0000x reference)
//
#include <hip/hip_runtime.h>

#define N_NODES 50000
#define N_EDGES 800000
#define D 128
#define MAXDEG 64  // Poisson(16) max over 50k nodes ~45; 64 safe (slots clamped)
#define EB 3125    // ceil(N_EDGES/256)
#define GB 1563    // ceil(N_NODES/32)

// ---------------------------------------------------------------------------
__device__ inline unsigned short f2bf(float f) {  // round-to-nearest-even
    unsigned u = __float_as_uint(f);
    unsigned r = (u + 0x7fffu + ((u >> 16) & 1u)) >> 16;
    return (unsigned short)r;
}

// ---------------------------------------------------------------------------
// GEMM body: Yb[r,:](bf16) = scale[r] * (X[r,:] @ W), scale = dinv or 1.
__device__ inline void gemm_body(int bb, const float* __restrict__ X,
                                 const float* __restrict__ W,
                                 const float* __restrict__ dinv,  // may be null
                                 unsigned short* __restrict__ Yb,
                                 float* sX) {
    int row0 = bb * 32;
    int nr = min(32, N_NODES - row0);
    {
        const float4* xs = (const float4*)(X + (size_t)row0 * D);
        float4* xd = (float4*)sX;
        int nvec = nr * (D / 4);
        for (int i = threadIdx.x; i < nvec; i += 256) xd[i] = xs[i];
    }
    __syncthreads();
    int tx = threadIdx.x & 31;  // cols [4*tx, 4*tx+3]
    int ty = threadIdx.x >> 5;  // rows [4*ty, 4*ty+3]
    float acc[4][4] = {{0.f}};
    for (int k = 0; k < D; k += 4) {
        float4 a[4], b[4];
        #pragma unroll
        for (int i = 0; i < 4; ++i) a[i] = *(float4*)&sX[(ty * 4 + i) * D + k];
        #pragma unroll
        for (int j = 0; j < 4; ++j) b[j] = *(const float4*)(W + (k + j) * D + tx * 4);
        #pragma unroll
        for (int i = 0; i < 4; ++i) {
            float ai[4] = {a[i].x, a[i].y, a[i].z, a[i].w};
            #pragma unroll
            for (int j = 0; j < 4; ++j) {
                acc[i][0] += ai[j] * b[j].x;
                acc[i][1] += ai[j] * b[j].y;
                acc[i][2] += ai[j] * b[j].z;
                acc[i][3] += ai[j] * b[j].w;
            }
        }
    }
    #pragma unroll
    for (int i = 0; i < 4; ++i) {
        int r = row0 + ty * 4 + i;
        if (r < N_NODES) {
            float dr = dinv ? dinv[r] : 1.f;
            ushort4 o;
            o.x = f2bf(acc[i][0] * dr);
            o.y = f2bf(acc[i][1] * dr);
            o.z = f2bf(acc[i][2] * dr);
            o.w = f2bf(acc[i][3] * dr);
            *(ushort4*)(Yb + (size_t)r * D + tx * 4) = o;
        }
    }
}

// ---------------------------------------------------------------------------
// Fused: blocks [0,EB) build padded CSR (1 atomic + 1 store per edge, the
// latency/write-through-bound part); blocks [EB,EB+GB) run GEMM1 (VALU-bound).
// The two co-schedule on separate pipes -> count's atomic wall hides GEMM1.
__global__ __launch_bounds__(256) void k_count_gemm1(
        const int* __restrict__ src, const int* __restrict__ dst,
        const float* __restrict__ ew, int* __restrict__ cnt,
        unsigned* __restrict__ csr,
        const float* __restrict__ X, const float* __restrict__ W,
        unsigned short* __restrict__ Yb) {
    __shared__ float sX[32 * D];  // used by gemm blocks only
    if (blockIdx.x < EB) {
        int e = blockIdx.x * 256 + threadIdx.x;
        if (e < N_EDGES) {
            int d = dst[e];
            int s = src[e];
            float w = ew[e];
            int old = atomicAdd(&cnt[d], 1);
            int slot = min(old, MAXDEG - 1);
            unsigned wf = min(__float2uint_rn(w * 65536.f), 65535u);
            csr[d * MAXDEG + slot] = ((unsigned)s << 16) | wf;
        }
        return;
    }
    gemm_body(blockIdx.x - EB, X, W, nullptr, Yb, sX);
}

// Standalone GEMM (layer 2, dinv folded into epilogue)
__global__ __launch_bounds__(256) void k_gemm(const float* __restrict__ X,
                                              const float* __restrict__ W,
                                              const float* __restrict__ dinv,
                                              unsigned short* __restrict__ Yb) {
    __shared__ float sX[32 * D];
    gemm_body(blockIdx.x, X, W, dinv, Yb, sX);
}

// ---------------------------------------------------------------------------
// Node-parallel: deg = sum of quantized w over the node's CSR segment -> dinv.
__global__ __launch_bounds__(256) void k_dinv(const int* __restrict__ cnt,
                                              const unsigned* __restrict__ csr,
                                              float* __restrict__ dinv) {
    int node = blockIdx.x * 16 + ((threadIdx.x >> 6) << 2) + ((threadIdx.x & 63) >> 4);
    int j = threadIdx.x & 15;
    int c = min(cnt[node], MAXDEG);
    float sum = 0.f;
    for (int k = j; k < c; k += 16)
        sum += (float)(csr[node * MAXDEG + k] & 0xffffu);
    sum *= (1.f / 65536.f);
    #pragma unroll
    for (int off = 1; off < 16; off <<= 1) sum += __shfl_xor(sum, off, 64);
    if (j == 0) dinv[node] = sum > 0.f ? rsqrtf(fmaxf(sum, 1e-30f)) : 0.f;
}

// ---------------------------------------------------------------------------
// Gather-aggregate from bf16 H. Wave per node: 4 edge-subgroups x 16 feature
// lanes. Each subgroup loads its 4 CSR entries as ONE dwordx4 broadcast, then
// issues all 4 row-gathers back-to-back -> 16 rows in flight per wave, csr
// latency paid once per 16 edges. Tail predicated by group-uniform branches.
// use_dinv_src: layer-1 path multiplies per-edge dinv[s] (wave-uniform 4B
// broadcast from the L2-resident 200KB table).
__global__ __launch_bounds__(256) void k_aggregate(const uint4* __restrict__ H4,
                                                   const int* __restrict__ cnt,
                                                   const unsigned* __restrict__ csr,
                                                   const float* __restrict__ dinv,
                                                   const float* __restrict__ bias,
                                                   float* __restrict__ out,
                                                   int relu, int use_dinv_src) {
    int node = blockIdx.x * 4 + (threadIdx.x >> 6);
    int lane = threadIdx.x & 63;
    int g = lane >> 4;    // edge subgroup 0..3
    int fl = lane & 15;   // feature lane: features [fl*8, fl*8+7]
    int end = min(cnt[node], MAXDEG);
    const uint4* row4 = (const uint4*)(csr + (size_t)node * MAXDEG);
    float acc[8] = {0.f, 0.f, 0.f, 0.f, 0.f, 0.f, 0.f, 0.f};
    for (int base = 0; base < end; base += 16) {
        int k0 = base + g * 4;
        if (k0 < end) {
            uint4 c4 = row4[(base >> 2) + g];  // 16B-aligned broadcast
            unsigned cs[4] = {c4.x, c4.y, c4.z, c4.w};
            #pragma unroll
            for (int j = 0; j < 4; ++j) {
                if (k0 + j < end) {  // group-uniform predicate
                    unsigned s = cs[j] >> 16;
                    float nm = (float)(cs[j] & 0xffffu) * (1.f / 65536.f);
                    if (use_dinv_src) nm *= dinv[s];
                    uint4 u = H4[(size_t)s * (D / 8) + fl];
                    unsigned a0[4] = {u.x, u.y, u.z, u.w};
                    #pragma unroll
                    for (int q = 0; q < 4; ++q) {
                        acc[2 * q]     += __uint_as_float(a0[q] << 16) * nm;
                        acc[2 * q + 1] += __uint_as_float(a0[q] & 0xffff0000u) * nm;
                    }
                }
            }
        }
    }
    // reduce the 4 edge-subgroups (feature f lives in lanes fl, fl+16, +32, +48)
    #pragma unroll
    for (int j = 0; j < 8; ++j) {
        acc[j] += __shfl_xor(acc[j], 16, 64);
        acc[j] += __shfl_xor(acc[j], 32, 64);
    }
    if (g < 2) {  // 32 lanes write the 512 B output row
        float dn = dinv[node];
        int f = fl * 8 + g * 4;
        float4 o = make_float4(acc[g * 4 + 0] * dn + bias[f + 0],
                               acc[g * 4 + 1] * dn + bias[f + 1],
                               acc[g * 4 + 2] * dn + bias[f + 2],
                               acc[g * 4 + 3] * dn + bias[f + 3]);
        if (relu) {
            o.x = fmaxf(o.x, 0.f); o.y = fmaxf(o.y, 0.f);
            o.z = fmaxf(o.z, 0.f); o.w = fmaxf(o.w, 0.f);
        }
        *(float4*)(out + (size_t)node * D + f) = o;
    }
}

// ---------------------------------------------------------------------------
extern "C" void kernel_launch(void* const* d_in, const int* in_sizes, int n_in,
                              void* d_out, int out_size, void* d_ws, size_t ws_size,
                              hipStream_t stream) {
    const float* x   = (const float*)d_in[0];
    const int*   ei  = (const int*)d_in[1];   // [2, E] int32
    const float* ew  = (const float*)d_in[2];
    const float* W1  = (const float*)d_in[3];
    const float* b1  = (const float*)d_in[4];
    const float* W2  = (const float*)d_in[5];
    const float* b2  = (const float*)d_in[6];
    float* out = (float*)d_out;

    const int* src = ei;
    const int* dst = ei + N_EDGES;

    char* base = (char*)d_ws;
    size_t off = 0;
    auto take = [&](size_t bytes) -> char* {
        char* p = base + off;
        off += (bytes + 255) & ~(size_t)255;
        return p;
    };
    int*      cnt  = (int*)take(N_NODES * 4);
    size_t zero_bytes = off;  // cnt only
    float*    dinv = (float*)take(N_NODES * 4);
    unsigned* csr  = (unsigned*)take((size_t)N_NODES * MAXDEG * 4);        // 12.8 MB
    unsigned short* h0 = (unsigned short*)take((size_t)N_NODES * D * 2);   // bf16 H
    float*    h1   = (float*)take((size_t)N_NODES * D * 4);                // agg1 out

    hipMemsetAsync(d_ws, 0, zero_bytes, stream);

    const int DB = (N_NODES + 15) / 16;     // 3125
    const int AB = N_NODES / 4;             // 12500 (exact)

    // CSR build + GEMM1 fused (independent work, count first in dispatch order)
    k_count_gemm1<<<EB + GB, 256, 0, stream>>>(src, dst, ew, cnt, csr, x, W1, h0);
    k_dinv<<<DB, 256, 0, stream>>>(cnt, csr, dinv);

    // layer 1 aggregate: per-edge dinv[s] (h0 is raw x@W1)
    k_aggregate<<<AB, 256, 0, stream>>>((const uint4*)h0, cnt, csr, dinv, b1, h1, 1, 1);

    // layer 2: dinv folded into GEMM epilogue
    k_gemm<<<GB, 256, 0, stream>>>(h1, W2, dinv, h0);
    k_aggregate<<<AB, 256, 0, stream>>>((const uint4*)h0, cnt, csr, dinv, b2, out, 0, 0);
}

// Round 6
// 279.477 us; speedup vs baseline: 1.0144x; 1.0144x over previous
//
#include <hip/hip_runtime.h>

#define N_NODES 50000
#define N_EDGES 800000
#define D 128
#define MAXDEG 64  // Poisson(16) max over 50k nodes ~45; 64 safe (slots clamped)

typedef __attribute__((ext_vector_type(8))) short bf16x8;
typedef __attribute__((ext_vector_type(4))) float f32x4;

// ---------------------------------------------------------------------------
__device__ inline unsigned short f2bf(float f) {  // round-to-nearest-even
    unsigned u = __float_as_uint(f);
    unsigned r = (u + 0x7fffu + ((u >> 16) & 1u)) >> 16;
    return (unsigned short)r;
}

// ---------------------------------------------------------------------------
// One pass over edges: atomicAdd returns slot in dst's padded segment;
// store (src<<16 | w_fix16). 1 atomic + 1 store per edge. (Round-4 form —
// round-5 fusion with GEMM1 regressed; atomic wall is not hideable in-dispatch.)
__global__ __launch_bounds__(256) void k_count(const int* __restrict__ src,
                                               const int* __restrict__ dst,
                                               const float* __restrict__ ew,
                                               int* __restrict__ cnt,
                                               unsigned* __restrict__ csr) {
    int e = blockIdx.x * 256 + threadIdx.x;
    if (e >= N_EDGES) return;
    int d = dst[e];
    int s = src[e];
    float w = ew[e];
    int old = atomicAdd(&cnt[d], 1);
    int slot = min(old, MAXDEG - 1);
    unsigned wf = min(__float2uint_rn(w * 65536.f), 65535u);
    csr[d * MAXDEG + slot] = ((unsigned)s << 16) | wf;
}

// ---------------------------------------------------------------------------
// Wt[n][k] = bf16(W[k][n]) for both layer weights (B-operand wants n-major,
// k-contiguous so each lane's 8-k fragment is one 16B load).
__global__ __launch_bounds__(256) void k_prepW(const float* __restrict__ W1,
                                               const float* __restrict__ W2,
                                               unsigned short* __restrict__ Wt1,
                                               unsigned short* __restrict__ Wt2) {
    const float* W = blockIdx.x ? W2 : W1;
    unsigned short* Wt = blockIdx.x ? Wt2 : Wt1;
    for (int idx = threadIdx.x; idx < D * D; idx += 256) {
        int n = idx & 127, k = idx >> 7;
        Wt[n * D + k] = f2bf(W[k * D + n]);
    }
}

// ---------------------------------------------------------------------------
// Node-parallel: deg = sum of quantized w over the node's CSR segment -> dinv.
__global__ __launch_bounds__(256) void k_dinv(const int* __restrict__ cnt,
                                              const unsigned* __restrict__ csr,
                                              float* __restrict__ dinv) {
    int node = blockIdx.x * 16 + ((threadIdx.x >> 6) << 2) + ((threadIdx.x & 63) >> 4);
    int j = threadIdx.x & 15;
    int c = min(cnt[node], MAXDEG);
    float sum = 0.f;
    for (int k = j; k < c; k += 16)
        sum += (float)(csr[node * MAXDEG + k] & 0xffffu);
    sum *= (1.f / 65536.f);
    #pragma unroll
    for (int off = 1; off < 16; off <<= 1) sum += __shfl_xor(sum, off, 64);
    if (j == 0) dinv[node] = sum > 0.f ? rsqrtf(fmaxf(sum, 1e-30f)) : 0.f;
}

// ---------------------------------------------------------------------------
// MFMA GEMM: Yb[r,:](bf16) = scale[r] * (X[r,:] @ W)  via 16x16x32 bf16 MFMA.
// Block = 256 thr = 4 waves; wave w computes rows [row0+16w, row0+16w+16) x 128.
// A: X tile staged to LDS as bf16 (fp32 converted in-flight when xIsF32);
//    lane frag = A[m=lane&15][k = quad*8 + j], one ds_read_b128.
// B: Wt[n][k] bf16 from global (32 KB, L1-resident); lane frag = 16B load.
// C/D: col=lane&15, row=quad*4+reg (verified m89/m91); epilogue reorganizes
// through the wave's private LDS slice, stores coalesced ushort rows.
__global__ __launch_bounds__(256) void k_gemm(const void* __restrict__ Xv,
                                              const unsigned short* __restrict__ Wt,
                                              const float* __restrict__ dinv,  // null => 1
                                              unsigned short* __restrict__ Yb,
                                              int xIsF32) {
    __shared__ unsigned short sX[64 * D];  // 16 KB bf16 tile, 64 rows
    int row0 = blockIdx.x * 64;
    int nr = min(64, N_NODES - row0);
    if (xIsF32) {
        const float4* xs = (const float4*)((const float*)Xv + (size_t)row0 * D);
        int nvec = nr * (D / 4);
        for (int i = threadIdx.x; i < nvec; i += 256) {
            float4 v = xs[i];
            ushort4 o;
            o.x = f2bf(v.x); o.y = f2bf(v.y); o.z = f2bf(v.z); o.w = f2bf(v.w);
            *(ushort4*)(sX + i * 4) = o;
        }
    } else {
        const uint4* xs = (const uint4*)((const unsigned short*)Xv + (size_t)row0 * D);
        int nvec = nr * (D / 8);
        for (int i = threadIdx.x; i < nvec; i += 256)
            *(uint4*)(sX + i * 8) = xs[i];
    }
    __syncthreads();

    int wave = threadIdx.x >> 6, lane = threadIdx.x & 63;
    int m = lane & 15, quad = lane >> 4;
    f32x4 acc[8];
    #pragma unroll
    for (int i = 0; i < 8; ++i) acc[i] = (f32x4){0.f, 0.f, 0.f, 0.f};

    const unsigned short* aBase = sX + (wave * 16 + m) * D + quad * 8;
    #pragma unroll
    for (int c = 0; c < 4; ++c) {  // k-chunks of 32
        bf16x8 a = *(const bf16x8*)(aBase + c * 32);
        #pragma unroll
        for (int n0 = 0; n0 < 8; ++n0) {
            bf16x8 b = *(const bf16x8*)(Wt + (n0 * 16 + m) * D + c * 32 + quad * 8);
            acc[n0] = __builtin_amdgcn_mfma_f32_16x16x32_bf16(a, b, acc[n0], 0, 0, 0);
        }
    }

    // per-row scale (dinv fold); rows of this lane's C frags: quad*4 + i
    float dv[4];
    #pragma unroll
    for (int i = 0; i < 4; ++i) {
        int r = row0 + wave * 16 + quad * 4 + i;
        dv[i] = dinv ? (r < N_NODES ? dinv[r] : 0.f) : 1.f;
    }

    // epilogue: write C-layout into the wave's own 4 KB LDS slice, read row-major
    unsigned short* sOut = sX + wave * 16 * D;
    __syncthreads();  // all waves done reading their A rows
    #pragma unroll
    for (int n0 = 0; n0 < 8; ++n0)
        #pragma unroll
        for (int i = 0; i < 4; ++i)
            sOut[(quad * 4 + i) * D + n0 * 16 + m] = f2bf(acc[n0][i] * dv[i]);
    __syncthreads();
    int rr = lane >> 2, c0 = (lane & 3) * 32;
    int grow = row0 + wave * 16 + rr;
    if (grow < N_NODES) {
        uint4* dstp = (uint4*)(Yb + (size_t)grow * D + c0);
        const uint4* srcp = (const uint4*)(sOut + rr * D + c0);
        dstp[0] = srcp[0]; dstp[1] = srcp[1]; dstp[2] = srcp[2]; dstp[3] = srcp[3];
    }
}

// ---------------------------------------------------------------------------
// Gather-aggregate from bf16 H' (= dinv[s] * h[s], fold done in GEMM epilogue):
//   out[n] = (relu?)( dinv[n] * sum_k w_k * H'[s_k] + b )
// Wave per node: 4 edge-subgroups x 16 feature-lanes; each subgroup loads its
// 4 CSR entries as ONE dwordx4 broadcast then issues 4 row-gathers
// back-to-back -> 16 rows in flight per wave. out_bf16: layer-1 writes bf16 h1.
__global__ __launch_bounds__(256) void k_aggregate(const uint4* __restrict__ H4,
                                                   const int* __restrict__ cnt,
                                                   const unsigned* __restrict__ csr,
                                                   const float* __restrict__ dinv,
                                                   const float* __restrict__ bias,
                                                   void* __restrict__ out,
                                                   int relu, int out_bf16) {
    int node = blockIdx.x * 4 + (threadIdx.x >> 6);
    int lane = threadIdx.x & 63;
    int g = lane >> 4;    // edge subgroup 0..3
    int fl = lane & 15;   // feature lane: features [fl*8, fl*8+7]
    int end = min(cnt[node], MAXDEG);
    const uint4* row4 = (const uint4*)(csr + (size_t)node * MAXDEG);
    float acc[8] = {0.f, 0.f, 0.f, 0.f, 0.f, 0.f, 0.f, 0.f};
    for (int base = 0; base < end; base += 16) {
        int k0 = base + g * 4;
        if (k0 < end) {
            uint4 c4 = row4[(base >> 2) + g];
            unsigned cs[4] = {c4.x, c4.y, c4.z, c4.w};
            #pragma unroll
            for (int j = 0; j < 4; ++j) {
                if (k0 + j < end) {  // group-uniform predicate
                    unsigned s = cs[j] >> 16;
                    float nm = (float)(cs[j] & 0xffffu) * (1.f / 65536.f);
                    uint4 u = H4[(size_t)s * (D / 8) + fl];
                    unsigned a0[4] = {u.x, u.y, u.z, u.w};
                    #pragma unroll
                    for (int q = 0; q < 4; ++q) {
                        acc[2 * q]     += __uint_as_float(a0[q] << 16) * nm;
                        acc[2 * q + 1] += __uint_as_float(a0[q] & 0xffff0000u) * nm;
                    }
                }
            }
        }
    }
    #pragma unroll
    for (int j = 0; j < 8; ++j) {
        acc[j] += __shfl_xor(acc[j], 16, 64);
        acc[j] += __shfl_xor(acc[j], 32, 64);
    }
    if (g < 2) {
        float dn = dinv[node];
        int f = fl * 8 + g * 4;
        float v[4];
        #pragma unroll
        for (int j = 0; j < 4; ++j) {
            v[j] = acc[g * 4 + j] * dn + bias[f + j];
            if (relu) v[j] = fmaxf(v[j], 0.f);
        }
        if (out_bf16) {
            ushort4 o;
            o.x = f2bf(v[0]); o.y = f2bf(v[1]); o.z = f2bf(v[2]); o.w = f2bf(v[3]);
            *(ushort4*)((unsigned short*)out + (size_t)node * D + f) = o;
        } else {
            *(float4*)((float*)out + (size_t)node * D + f) =
                make_float4(v[0], v[1], v[2], v[3]);
        }
    }
}

// ---------------------------------------------------------------------------
extern "C" void kernel_launch(void* const* d_in, const int* in_sizes, int n_in,
                              void* d_out, int out_size, void* d_ws, size_t ws_size,
                              hipStream_t stream) {
    const float* x   = (const float*)d_in[0];
    const int*   ei  = (const int*)d_in[1];   // [2, E] int32
    const float* ew  = (const float*)d_in[2];
    const float* W1  = (const float*)d_in[3];
    const float* b1  = (const float*)d_in[4];
    const float* W2  = (const float*)d_in[5];
    const float* b2  = (const float*)d_in[6];
    float* out = (float*)d_out;

    const int* src = ei;
    const int* dst = ei + N_EDGES;

    char* base = (char*)d_ws;
    size_t off = 0;
    auto take = [&](size_t bytes) -> char* {
        char* p = base + off;
        off += (bytes + 255) & ~(size_t)255;
        return p;
    };
    int*      cnt  = (int*)take(N_NODES * 4);
    size_t zero_bytes = off;  // cnt only
    float*    dinv = (float*)take(N_NODES * 4);
    unsigned* csr  = (unsigned*)take((size_t)N_NODES * MAXDEG * 4);        // 12.8 MB
    unsigned short* Wt1 = (unsigned short*)take(D * D * 2);
    unsigned short* Wt2 = (unsigned short*)take(D * D * 2);
    unsigned short* h0  = (unsigned short*)take((size_t)N_NODES * D * 2);  // bf16 H'
    unsigned short* h1  = (unsigned short*)take((size_t)N_NODES * D * 2);  // bf16 agg1

    hipMemsetAsync(d_ws, 0, zero_bytes, stream);

    const int EB = (N_EDGES + 255) / 256;   // 3125
    const int DB = (N_NODES + 15) / 16;     // 3125
    const int GB = (N_NODES + 63) / 64;     // 782
    const int AB = N_NODES / 4;             // 12500

    k_count<<<EB, 256, 0, stream>>>(src, dst, ew, cnt, csr);
    k_prepW<<<2, 256, 0, stream>>>(W1, W2, Wt1, Wt2);
    k_dinv<<<DB, 256, 0, stream>>>(cnt, csr, dinv);

    // layer 1: h0 = bf16(dinv * (x @ W1)); agg1 -> bf16 h1 (+relu)
    k_gemm<<<GB, 256, 0, stream>>>(x, Wt1, dinv, h0, 1);
    k_aggregate<<<AB, 256, 0, stream>>>((const uint4*)h0, cnt, csr, dinv, b1, h1, 1, 1);

    // layer 2: h0 = bf16(dinv * (h1 @ W2)); agg2 -> fp32 out
    k_gemm<<<GB, 256, 0, stream>>>(h1, Wt2, dinv, h0, 0);
    k_aggregate<<<AB, 256, 0, stream>>>((const uint4*)h0, cnt, csr, dinv, b2, out, 0, 0);
}

// Round 7
// 237.802 us; speedup vs baseline: 1.1921x; 1.1753x over previous
//
#include <hip/hip_runtime.h>

#define N_NODES 50000
#define N_EDGES 800000
#define D 128
#define MAXDEG 64    // Poisson(16) max deg over 50k nodes ~45; slots clamped
#define NBUCK 196    // coarse bucket = dst>>8 (256 nodes/bucket)
#define BUCKCAP 5120 // expected 4096/bucket, +16 sigma
#define EB1 391      // ceil(800000/2048)

typedef __attribute__((ext_vector_type(8))) short bf16x8;
typedef __attribute__((ext_vector_type(4))) float f32x4;

// ---------------------------------------------------------------------------
__device__ inline unsigned short f2bf(float f) {  // round-to-nearest-even
    unsigned u = __float_as_uint(f);
    unsigned r = (u + 0x7fffu + ((u >> 16) & 1u)) >> 16;
    return (unsigned short)r;
}

// ---------------------------------------------------------------------------
// Pass 1: coarse-bucket the edges. Per wg: LDS histogram over 196 buckets,
// ONE global atomic per (wg,bucket) to reserve a contiguous slice, then
// scatter entries into the wg's own slice (L2 merges -> dense write-back).
// Replaces 800k scattered stores+atomics (48MB write-through) with ~77k
// atomics + 6.4MB dense writes. Blocks [EB1,EB1+2) do the W transpose.
__global__ __launch_bounds__(256) void k_bucket(const int* __restrict__ src,
                                                const int* __restrict__ dst,
                                                const float* __restrict__ ew,
                                                int* __restrict__ cursor,
                                                uint2* __restrict__ buck,
                                                const float* __restrict__ W1,
                                                const float* __restrict__ W2,
                                                unsigned short* __restrict__ Wt1,
                                                unsigned short* __restrict__ Wt2) {
    if (blockIdx.x >= EB1) {  // fold k_prepW: Wt[n][k] = bf16(W[k][n])
        const float* W = (blockIdx.x == EB1) ? W1 : W2;
        unsigned short* Wt = (blockIdx.x == EB1) ? Wt1 : Wt2;
        for (int idx = threadIdx.x; idx < D * D; idx += 256) {
            int n = idx & 127, k = idx >> 7;
            Wt[n * D + k] = f2bf(W[k * D + n]);
        }
        return;
    }
    __shared__ int hist[NBUCK];
    __shared__ int base[NBUCK];
    for (int i = threadIdx.x; i < NBUCK; i += 256) hist[i] = 0;
    __syncthreads();
    int e0 = blockIdx.x * 2048 + threadIdx.x;
    int dl[8]; unsigned pay[8]; int bk[8]; bool val[8];
    #pragma unroll
    for (int j = 0; j < 8; ++j) {
        int e = e0 + j * 256;
        val[j] = e < N_EDGES;
        if (val[j]) {
            dl[j] = dst[e];
            int s = src[e];
            unsigned wf = min(__float2uint_rn(ew[e] * 65536.f), 65535u);
            pay[j] = ((unsigned)s << 16) | wf;
            bk[j] = dl[j] >> 8;
            atomicAdd(&hist[bk[j]], 1);
        }
    }
    __syncthreads();
    for (int i = threadIdx.x; i < NBUCK; i += 256) {
        int h = hist[i];
        base[i] = h ? atomicAdd(&cursor[i], h) : 0;
    }
    __syncthreads();
    for (int i = threadIdx.x; i < NBUCK; i += 256) hist[i] = 0;
    __syncthreads();
    #pragma unroll
    for (int j = 0; j < 8; ++j) {
        if (val[j]) {
            int slot = base[bk[j]] + atomicAdd(&hist[bk[j]], 1);
            if (slot < BUCKCAP)
                buck[(size_t)bk[j] * BUCKCAP + slot] = make_uint2(pay[j], dl[j] & 255);
        }
    }
}

// ---------------------------------------------------------------------------
// Pass 2: one wg per bucket. Coalesced read of the bucket's entries, LDS-atomic
// slotting into a 64KB LDS padded-CSR image (256 nodes x 64 slots) + integer
// degree accumulation, then fully dense coalesced write-out of csr/cnt/dinv.
__global__ __launch_bounds__(256) void k_build(const int* __restrict__ cursor,
                                               const uint2* __restrict__ buck,
                                               unsigned* __restrict__ csr,
                                               int* __restrict__ cnt,
                                               float* __restrict__ dinv) {
    __shared__ unsigned csr_loc[256 * MAXDEG];  // 64 KB
    __shared__ int cnt_loc[256];
    __shared__ int deg_loc[256];                // sum of w_fix16 (exact in int)
    int b = blockIdx.x;
    cnt_loc[threadIdx.x] = 0;
    deg_loc[threadIdx.x] = 0;
    __syncthreads();
    int n = min(cursor[b], BUCKCAP);
    const uint2* bb = buck + (size_t)b * BUCKCAP;
    for (int i = threadIdx.x; i < n; i += 256) {
        uint2 e = bb[i];
        int ln = e.y;
        int slot = atomicAdd(&cnt_loc[ln], 1);
        if (slot < MAXDEG) csr_loc[ln * MAXDEG + slot] = e.x;
        atomicAdd(&deg_loc[ln], (int)(e.x & 0xffffu));
    }
    __syncthreads();
    int node0 = b * 256;
    int nnodes = min(256, N_NODES - node0);  // last bucket: 80 nodes
    uint4* g = (uint4*)(csr + (size_t)node0 * MAXDEG);
    const uint4* l = (const uint4*)csr_loc;
    int nv = nnodes * (MAXDEG / 4);
    for (int i = threadIdx.x; i < nv; i += 256) g[i] = l[i];
    if (threadIdx.x < nnodes) {
        int node = node0 + threadIdx.x;
        cnt[node] = min(cnt_loc[threadIdx.x], MAXDEG);
        float sum = (float)deg_loc[threadIdx.x] * (1.f / 65536.f);
        dinv[node] = sum > 0.f ? rsqrtf(fmaxf(sum, 1e-30f)) : 0.f;
    }
}

// ---------------------------------------------------------------------------
// MFMA GEMM: Yb[r,:](bf16) = scale[r] * (X[r,:] @ W)  via 16x16x32 bf16 MFMA.
__global__ __launch_bounds__(256) void k_gemm(const void* __restrict__ Xv,
                                              const unsigned short* __restrict__ Wt,
                                              const float* __restrict__ dinv,
                                              unsigned short* __restrict__ Yb,
                                              int xIsF32) {
    __shared__ unsigned short sX[64 * D];  // 16 KB bf16 tile, 64 rows
    int row0 = blockIdx.x * 64;
    int nr = min(64, N_NODES - row0);
    if (xIsF32) {
        const float4* xs = (const float4*)((const float*)Xv + (size_t)row0 * D);
        int nvec = nr * (D / 4);
        for (int i = threadIdx.x; i < nvec; i += 256) {
            float4 v = xs[i];
            ushort4 o;
            o.x = f2bf(v.x); o.y = f2bf(v.y); o.z = f2bf(v.z); o.w = f2bf(v.w);
            *(ushort4*)(sX + i * 4) = o;
        }
    } else {
        const uint4* xs = (const uint4*)((const unsigned short*)Xv + (size_t)row0 * D);
        int nvec = nr * (D / 8);
        for (int i = threadIdx.x; i < nvec; i += 256)
            *(uint4*)(sX + i * 8) = xs[i];
    }
    __syncthreads();

    int wave = threadIdx.x >> 6, lane = threadIdx.x & 63;
    int m = lane & 15, quad = lane >> 4;
    f32x4 acc[8];
    #pragma unroll
    for (int i = 0; i < 8; ++i) acc[i] = (f32x4){0.f, 0.f, 0.f, 0.f};

    const unsigned short* aBase = sX + (wave * 16 + m) * D + quad * 8;
    #pragma unroll
    for (int c = 0; c < 4; ++c) {  // k-chunks of 32
        bf16x8 a = *(const bf16x8*)(aBase + c * 32);
        #pragma unroll
        for (int n0 = 0; n0 < 8; ++n0) {
            bf16x8 b = *(const bf16x8*)(Wt + (n0 * 16 + m) * D + c * 32 + quad * 8);
            acc[n0] = __builtin_amdgcn_mfma_f32_16x16x32_bf16(a, b, acc[n0], 0, 0, 0);
        }
    }

    float dv[4];
    #pragma unroll
    for (int i = 0; i < 4; ++i) {
        int r = row0 + wave * 16 + quad * 4 + i;
        dv[i] = dinv ? (r < N_NODES ? dinv[r] : 0.f) : 1.f;
    }

    unsigned short* sOut = sX + wave * 16 * D;
    __syncthreads();
    #pragma unroll
    for (int n0 = 0; n0 < 8; ++n0)
        #pragma unroll
        for (int i = 0; i < 4; ++i)
            sOut[(quad * 4 + i) * D + n0 * 16 + m] = f2bf(acc[n0][i] * dv[i]);
    __syncthreads();
    int rr = lane >> 2, c0 = (lane & 3) * 32;
    int grow = row0 + wave * 16 + rr;
    if (grow < N_NODES) {
        uint4* dstp = (uint4*)(Yb + (size_t)grow * D + c0);
        const uint4* srcp = (const uint4*)(sOut + rr * D + c0);
        dstp[0] = srcp[0]; dstp[1] = srcp[1]; dstp[2] = srcp[2]; dstp[3] = srcp[3];
    }
}

// ---------------------------------------------------------------------------
// Gather-aggregate from bf16 H' (= dinv[s]*h[s]):
//   out[n] = (relu?)( dinv[n] * sum_k w_k * H'[s_k] + b )
// Wave per node: 4 edge-subgroups x 16 feature lanes; per subgroup one dwordx4
// CSR broadcast then 4 back-to-back row gathers -> 16 rows in flight per wave.
__global__ __launch_bounds__(256) void k_aggregate(const uint4* __restrict__ H4,
                                                   const int* __restrict__ cnt,
                                                   const unsigned* __restrict__ csr,
                                                   const float* __restrict__ dinv,
                                                   const float* __restrict__ bias,
                                                   void* __restrict__ out,
                                                   int relu, int out_bf16) {
    int node = blockIdx.x * 4 + (threadIdx.x >> 6);
    int lane = threadIdx.x & 63;
    int g = lane >> 4;
    int fl = lane & 15;
    int end = min(cnt[node], MAXDEG);
    const uint4* row4 = (const uint4*)(csr + (size_t)node * MAXDEG);
    float acc[8] = {0.f, 0.f, 0.f, 0.f, 0.f, 0.f, 0.f, 0.f};
    for (int base = 0; base < end; base += 16) {
        int k0 = base + g * 4;
        if (k0 < end) {
            uint4 c4 = row4[(base >> 2) + g];
            unsigned cs[4] = {c4.x, c4.y, c4.z, c4.w};
            #pragma unroll
            for (int j = 0; j < 4; ++j) {
                if (k0 + j < end) {
                    unsigned s = cs[j] >> 16;
                    float nm = (float)(cs[j] & 0xffffu) * (1.f / 65536.f);
                    uint4 u = H4[(size_t)s * (D / 8) + fl];
                    unsigned a0[4] = {u.x, u.y, u.z, u.w};
                    #pragma unroll
                    for (int q = 0; q < 4; ++q) {
                        acc[2 * q]     += __uint_as_float(a0[q] << 16) * nm;
                        acc[2 * q + 1] += __uint_as_float(a0[q] & 0xffff0000u) * nm;
                    }
                }
            }
        }
    }
    #pragma unroll
    for (int j = 0; j < 8; ++j) {
        acc[j] += __shfl_xor(acc[j], 16, 64);
        acc[j] += __shfl_xor(acc[j], 32, 64);
    }
    if (g < 2) {
        float dn = dinv[node];
        int f = fl * 8 + g * 4;
        float v[4];
        #pragma unroll
        for (int j = 0; j < 4; ++j) {
            v[j] = acc[g * 4 + j] * dn + bias[f + j];
            if (relu) v[j] = fmaxf(v[j], 0.f);
        }
        if (out_bf16) {
            ushort4 o;
            o.x = f2bf(v[0]); o.y = f2bf(v[1]); o.z = f2bf(v[2]); o.w = f2bf(v[3]);
            *(ushort4*)((unsigned short*)out + (size_t)node * D + f) = o;
        } else {
            *(float4*)((float*)out + (size_t)node * D + f) =
                make_float4(v[0], v[1], v[2], v[3]);
        }
    }
}

// ---------------------------------------------------------------------------
extern "C" void kernel_launch(void* const* d_in, const int* in_sizes, int n_in,
                              void* d_out, int out_size, void* d_ws, size_t ws_size,
                              hipStream_t stream) {
    const float* x   = (const float*)d_in[0];
    const int*   ei  = (const int*)d_in[1];   // [2, E] int32
    const float* ew  = (const float*)d_in[2];
    const float* W1  = (const float*)d_in[3];
    const float* b1  = (const float*)d_in[4];
    const float* W2  = (const float*)d_in[5];
    const float* b2  = (const float*)d_in[6];
    float* out = (float*)d_out;

    const int* src = ei;
    const int* dst = ei + N_EDGES;

    char* base = (char*)d_ws;
    size_t off = 0;
    auto take = [&](size_t bytes) -> char* {
        char* p = base + off;
        off += (bytes + 255) & ~(size_t)255;
        return p;
    };
    int*      cursor = (int*)take(NBUCK * 4);
    size_t zero_bytes = off;  // cursor only
    float*    dinv = (float*)take(N_NODES * 4);
    int*      cnt  = (int*)take(N_NODES * 4);
    uint2*    buck = (uint2*)take((size_t)NBUCK * BUCKCAP * 8);            // 8.0 MB
    unsigned* csr  = (unsigned*)take((size_t)N_NODES * MAXDEG * 4);        // 12.8 MB
    unsigned short* Wt1 = (unsigned short*)take(D * D * 2);
    unsigned short* Wt2 = (unsigned short*)take(D * D * 2);
    unsigned short* h0  = (unsigned short*)take((size_t)N_NODES * D * 2);  // bf16 H'
    unsigned short* h1  = (unsigned short*)take((size_t)N_NODES * D * 2);  // bf16 agg1

    hipMemsetAsync(d_ws, 0, zero_bytes, stream);

    const int GB = (N_NODES + 63) / 64;     // 782
    const int AB = N_NODES / 4;             // 12500

    k_bucket<<<EB1 + 2, 256, 0, stream>>>(src, dst, ew, cursor, buck,
                                          W1, W2, Wt1, Wt2);
    k_build<<<NBUCK, 256, 0, stream>>>(cursor, buck, csr, cnt, dinv);

    // layer 1: h0 = bf16(dinv * (x @ W1)); agg1 -> bf16 h1 (+relu)
    k_gemm<<<GB, 256, 0, stream>>>(x, Wt1, dinv, h0, 1);
    k_aggregate<<<AB, 256, 0, stream>>>((const uint4*)h0, cnt, csr, dinv, b1, h1, 1, 1);

    // layer 2: h0 = bf16(dinv * (h1 @ W2)); agg2 -> fp32 out
    k_gemm<<<GB, 256, 0, stream>>>(h1, Wt2, dinv, h0, 0);
    k_aggregate<<<AB, 256, 0, stream>>>((const uint4*)h0, cnt, csr, dinv, b2, out, 0, 0);
}